// Round 10
// baseline (3768.687 us; speedup 1.0000x reference)
//
#include <hip/hip_runtime.h>
#include <hip/hip_bf16.h>

#define N_NODES 100000
#define N_EDGES 3200000
#define N_GRAPHS 256
#define D_IN 320
#define D_H 64

#define NBIN 391                    // ceil(N_NODES / 256) bins of 256 dst nodes
#define BIN_CAP 12288               // mean bin load 8186, sigma~90 -> +45 sigma
#define HIST_BLOCKS 256
#define HIST_CHUNK ((N_EDGES + HIST_BLOCKS - 1) / HIST_BLOCKS)
#define PART_BLOCKS 200
#define PART_CHUNK ((N_EDGES + PART_BLOCKS - 1) / PART_BLOCKS)   // 16000

#define GK 13                       // src buckets of 8192 nodes (2 MB of u)
#define NKEY (16 * GK * 16)         // (group, bucket, dl_low) keys per bin = 3328

// ---------------- CSR build (block-private chunk partition) ----------------

__global__ __launch_bounds__(256) void k_hist(const int* __restrict__ dst,
                                              int* __restrict__ ghist) {
    __shared__ int lh[NBIN];
    for (int i = threadIdx.x; i < NBIN; i += 256) lh[i] = 0;
    __syncthreads();
    int beg = blockIdx.x * HIST_CHUNK;
    int end = min(beg + HIST_CHUNK, N_EDGES);
    for (int e = beg + threadIdx.x; e < end; e += 256)
        atomicAdd(&lh[dst[e] >> 8], 1);
    __syncthreads();
    for (int i = threadIdx.x; i < NBIN; i += 256)
        if (lh[i]) atomicAdd(&ghist[i], lh[i]);
}

__global__ __launch_bounds__(512) void k_scanbins(const int* __restrict__ ghist,
                                                  int* __restrict__ binbase,
                                                  int* __restrict__ gcur) {
    __shared__ int sa[512], sb[512];
    int t = threadIdx.x;
    int v = (t < NBIN) ? ghist[t] : 0;
    sa[t] = v;
    __syncthreads();
    int* in = sa; int* out = sb;
    for (int off = 1; off < 512; off <<= 1) {
        out[t] = in[t] + (t >= off ? in[t - off] : 0);
        __syncthreads();
        int* tmp = in; in = out; out = tmp;
    }
    int excl = in[t] - v;
    if (t < NBIN) { binbase[t] = excl; gcur[t] = excl; }
    if (t == 511) binbase[NBIN] = in[511];
}

// partition edges into 391 bins; each block reserves a private contiguous
// chunk per bin (one global atomic per (block,bin)).
__global__ __launch_bounds__(256) void k_part(const int* __restrict__ src,
                                              const int* __restrict__ dst,
                                              int* __restrict__ gcur,
                                              int* __restrict__ ebuf) {
    __shared__ int lh[NBIN], gb[NBIN], cur[NBIN];
    for (int i = threadIdx.x; i < NBIN; i += 256) { lh[i] = 0; cur[i] = 0; }
    __syncthreads();
    int beg = blockIdx.x * PART_CHUNK;
    int end = min(beg + PART_CHUNK, N_EDGES);
    for (int e = beg + threadIdx.x; e < end; e += 256)
        atomicAdd(&lh[dst[e] >> 8], 1);
    __syncthreads();
    for (int i = threadIdx.x; i < NBIN; i += 256)
        gb[i] = lh[i] ? atomicAdd(&gcur[i], lh[i]) : 0;
    __syncthreads();
    for (int e = beg + threadIdx.x; e < end; e += 256) {
        int d = dst[e], s = src[e];
        int bin = d >> 8;
        int r = atomicAdd(&cur[bin], 1);
        ebuf[gb[bin] + r] = ((d & 255) << 17) | s;   // dst-low-8 | src(17b)
    }
}

// one block per bin: counting-sort by (group16, src_bucket, dl&15).
// Each 16-node group's edges end up contiguous, internally bucket-major.
// Emits rp4[bin][209] boundaries (208 = t index (g*13+k), 209th = bin end),
// col packed as (dl&15)<<17 | src, and dinv.
__global__ __launch_bounds__(256) void k_sortbin(const int* __restrict__ binbase,
                                                 const int* __restrict__ ebuf,
                                                 int* __restrict__ col,
                                                 int* __restrict__ rp4,
                                                 float* __restrict__ dinv) {
    __shared__ int hc[NKEY], sc[NKEY];
    __shared__ int sa[256], sb[256];
    __shared__ int scol[BIN_CAP];
    int b = blockIdx.x, t = threadIdx.x;
    int d0 = b << 8;
    int e0 = binbase[b], e1 = binbase[b + 1];
    for (int i = t; i < NKEY; i += 256) hc[i] = 0;
    __syncthreads();
    for (int i = e0 + t; i < e1; i += 256) {
        int pk = ebuf[i];
        int dl = pk >> 17, s = pk & 0x1FFFF;
        int key = (((dl >> 4) * GK + (s >> 13)) << 4) | (dl & 15);
        atomicAdd(&hc[key], 1);
    }
    __syncthreads();
    // thread t (<208) owns keys [t*16, t*16+16) == (g = t/13, k = t%13) chunk
    int loc[16]; int sum = 0;
    if (t < 208) {
#pragma unroll
        for (int q = 0; q < 16; ++q) { loc[q] = sum; sum += hc[t * 16 + q]; }
    }
    sa[t] = sum;
    __syncthreads();
    int* in = sa; int* out = sb;
    for (int o = 1; o < 256; o <<= 1) {
        out[t] = in[t] + (t >= o ? in[t - o] : 0);
        __syncthreads();
        int* tm = in; in = out; out = tm;
    }
    int tbase = in[t] - sum;
    if (t < 208) {
#pragma unroll
        for (int q = 0; q < 16; ++q) sc[t * 16 + q] = tbase + loc[q];
        rp4[b * 209 + t] = e0 + tbase;
    }
    if (t == 0) rp4[b * 209 + 208] = e1;
    // dinv: node n = d0 + t, degree = sum over buckets of hc[(g*13+k)*16+dl]
    int node = d0 + t;
    if (node < N_NODES) {
        int g = t >> 4, dl = t & 15, deg = 0;
#pragma unroll
        for (int k = 0; k < GK; ++k) deg += hc[((g * GK + k) << 4) | dl];
        dinv[node] = rsqrtf((float)(deg + 1));   // +1 self loop
    }
    __syncthreads();
    for (int i = e0 + t; i < e1; i += 256) {
        int pk = ebuf[i];
        int dl = pk >> 17, s = pk & 0x1FFFF;
        int key = (((dl >> 4) * GK + (s >> 13)) << 4) | (dl & 15);
        int p = atomicAdd(&sc[key], 1);
        if (p < BIN_CAP) scol[p] = ((dl & 15) << 17) | s;
    }
    __syncthreads();
    int n = e1 - e0;
    for (int i = t; i < n; i += 256) col[e0 + i] = scol[i];
}

// ---------------- tiled GEMM transform ----------------
// u[node][f] = (A[node,:] @ W)[f] * dinv[node]
template<int K>
__global__ __launch_bounds__(256) void k_gemm(const float* __restrict__ A,
                                              const float* __restrict__ W,
                                              const float* __restrict__ dinv,
                                              float* __restrict__ u) {
    __shared__ __align__(16) float xt[64][68];
    __shared__ __align__(16) float ws[64][68];
    int t = threadIdx.x;
    int ti = t & 15;
    int tj = t >> 4;
    int node0 = blockIdx.x * 64;
    float acc[4][4] = {{0.f}};

    for (int kc = 0; kc < K; kc += 64) {
        if (kc) __syncthreads();
#pragma unroll
        for (int p = 0; p < 4; ++p) {
            int m = tj + 16 * p;
            int node = node0 + m;
            if (node >= N_NODES) node = N_NODES - 1;
            float4 v = *(const float4*)(A + (size_t)node * K + kc + 4 * ti);
            xt[4 * ti + 0][m] = v.x;
            xt[4 * ti + 1][m] = v.y;
            xt[4 * ti + 2][m] = v.z;
            xt[4 * ti + 3][m] = v.w;
            float4 wv = *(const float4*)(W + (size_t)(kc + m) * D_H + 4 * ti);
            *(float4*)&ws[m][4 * ti] = wv;
        }
        __syncthreads();
#pragma unroll 16
        for (int k = 0; k < 64; ++k) {
            float4 xv = *(const float4*)&xt[k][4 * tj];
            float4 wv = *(const float4*)&ws[k][4 * ti];
            float xa[4] = {xv.x, xv.y, xv.z, xv.w};
            float wa[4] = {wv.x, wv.y, wv.z, wv.w};
#pragma unroll
            for (int i = 0; i < 4; ++i)
#pragma unroll
                for (int j = 0; j < 4; ++j)
                    acc[i][j] = fmaf(xa[i], wa[j], acc[i][j]);
        }
    }
#pragma unroll
    for (int i = 0; i < 4; ++i) {
        int node = node0 + 4 * tj + i;
        if (node < N_NODES) {
            float dv = dinv[node];
            float4 o = make_float4(acc[i][0] * dv, acc[i][1] * dv,
                                   acc[i][2] * dv, acc[i][3] * dv);
            *(float4*)(u + (size_t)node * D_H + 4 * ti) = o;
        }
    }
}

// ---------------- co-resident group aggregation ----------------
// One wave per 16-node group, all 6256 waves co-resident (1564 blocks,
// 16 KB LDS, 8 blocks/CU). Wave-private LDS accumulator, no barriers.
// Edges are bucket-major -> co-resident waves sweep the same 2 MB src
// window together.

__device__ __forceinline__ void group_gather(const float* __restrict__ uin,
                                             const int* __restrict__ col,
                                             int beg, int end,
                                             float* __restrict__ hw, int lane) {
    int e = beg;
    for (; e + 7 < end; e += 8) {               // 8 independent gathers in flight
        int p0 = col[e],     p1 = col[e + 1], p2 = col[e + 2], p3 = col[e + 3];
        int p4 = col[e + 4], p5 = col[e + 5], p6 = col[e + 6], p7 = col[e + 7];
        float v0 = uin[(size_t)(p0 & 0x1FFFF) * D_H + lane];
        float v1 = uin[(size_t)(p1 & 0x1FFFF) * D_H + lane];
        float v2 = uin[(size_t)(p2 & 0x1FFFF) * D_H + lane];
        float v3 = uin[(size_t)(p3 & 0x1FFFF) * D_H + lane];
        float v4 = uin[(size_t)(p4 & 0x1FFFF) * D_H + lane];
        float v5 = uin[(size_t)(p5 & 0x1FFFF) * D_H + lane];
        float v6 = uin[(size_t)(p6 & 0x1FFFF) * D_H + lane];
        float v7 = uin[(size_t)(p7 & 0x1FFFF) * D_H + lane];
        atomicAdd(&hw[((p0 >> 17) & 15) * 64 + lane], v0);
        atomicAdd(&hw[((p1 >> 17) & 15) * 64 + lane], v1);
        atomicAdd(&hw[((p2 >> 17) & 15) * 64 + lane], v2);
        atomicAdd(&hw[((p3 >> 17) & 15) * 64 + lane], v3);
        atomicAdd(&hw[((p4 >> 17) & 15) * 64 + lane], v4);
        atomicAdd(&hw[((p5 >> 17) & 15) * 64 + lane], v5);
        atomicAdd(&hw[((p6 >> 17) & 15) * 64 + lane], v6);
        atomicAdd(&hw[((p7 >> 17) & 15) * 64 + lane], v7);
    }
    for (; e < end; ++e) {
        int pk = col[e];
        atomicAdd(&hw[((pk >> 17) & 15) * 64 + lane],
                  uin[(size_t)(pk & 0x1FFFF) * D_H + lane]);
    }
}

// agg -> +self -> *dinv -> +b -> relu -> h
__global__ __launch_bounds__(256) void k_aggb(const float* __restrict__ uin,
                                              const int* __restrict__ rp4,
                                              const int* __restrict__ col,
                                              const float* __restrict__ dinv,
                                              const float* __restrict__ b,
                                              float* __restrict__ h) {
    __shared__ float hacc[4][16][64];
    int t = threadIdx.x, w = t >> 6, lane = t & 63;
    int grp = blockIdx.x * 4 + w;               // 0..6255
    int bin = grp >> 4, g = grp & 15;
    float* hw = &hacc[w][0][0];
#pragma unroll
    for (int j = 0; j < 16; ++j) hw[j * 64 + lane] = 0.f;
    const int* rpb = rp4 + bin * 209 + g * GK;
    group_gather(uin, col, rpb[0], rpb[GK], hw, lane);
    int nbase = (bin << 8) + (g << 4);
    float bl_ = b[lane];
    for (int j = 0; j < 16; ++j) {
        int n = nbase + j;
        if (n >= N_NODES) break;
        float acc = hw[j * 64 + lane] + uin[(size_t)n * D_H + lane];
        acc = acc * dinv[n] + bl_;
        h[(size_t)n * D_H + lane] = fmaxf(acc, 0.0f);
    }
}

// agg -> +self -> *dinv -> +b3 -> dot(Wl) -> val
__global__ __launch_bounds__(256) void k_aggb_dot(const float* __restrict__ uin,
                                                  const int* __restrict__ rp4,
                                                  const int* __restrict__ col,
                                                  const float* __restrict__ dinv,
                                                  const float* __restrict__ b,
                                                  const float* __restrict__ Wl,
                                                  float* __restrict__ val) {
    __shared__ float hacc[4][16][64];
    int t = threadIdx.x, w = t >> 6, lane = t & 63;
    int grp = blockIdx.x * 4 + w;
    int bin = grp >> 4, g = grp & 15;
    float* hw = &hacc[w][0][0];
#pragma unroll
    for (int j = 0; j < 16; ++j) hw[j * 64 + lane] = 0.f;
    const int* rpb = rp4 + bin * 209 + g * GK;
    group_gather(uin, col, rpb[0], rpb[GK], hw, lane);
    int nbase = (bin << 8) + (g << 4);
    float bl_ = b[lane], wl = Wl[lane];
    for (int j = 0; j < 16; ++j) {
        int n = nbase + j;
        if (n >= N_NODES) break;
        float acc = hw[j * 64 + lane] + uin[(size_t)n * D_H + lane];
        float v = (acc * dinv[n] + bl_) * wl;
#pragma unroll
        for (int m = 32; m > 0; m >>= 1) v += __shfl_xor(v, m, 64);
        if (lane == 0) val[n] = v;
    }
}

// one block per graph: batch is sorted, binary-search the segment, reduce.
__global__ __launch_bounds__(256) void k_gpool(const float* __restrict__ val,
                                               const int* __restrict__ batch,
                                               const float* __restrict__ bl,
                                               float* __restrict__ out) {
    int g = blockIdx.x;
    int l = 0, r = N_NODES;
    while (l < r) { int m = (l + r) >> 1; if (batch[m] < g) l = m + 1; else r = m; }
    int lo = l;
    r = N_NODES;
    while (l < r) { int m = (l + r) >> 1; if (batch[m] < g + 1) l = m + 1; else r = m; }
    int hi = l;
    float s = 0.0f;
    for (int i = lo + threadIdx.x; i < hi; i += 256) s += val[i];
#pragma unroll
    for (int m = 32; m > 0; m >>= 1) s += __shfl_xor(s, m, 64);
    __shared__ float red[4];
    int wid = threadIdx.x >> 6, lane = threadIdx.x & 63;
    if (lane == 0) red[wid] = s;
    __syncthreads();
    if (threadIdx.x == 0) {
        float t = red[0] + red[1] + red[2] + red[3];
        out[g] = t / fmaxf((float)(hi - lo), 1.0f) + bl[0];
    }
}

// ---------------- launch ----------------

extern "C" void kernel_launch(void* const* d_in, const int* in_sizes, int n_in,
                              void* d_out, int out_size, void* d_ws, size_t ws_size,
                              hipStream_t stream) {
    const float* x   = (const float*)d_in[0];
    const int*   ei  = (const int*)d_in[1];
    const int*   bat = (const int*)d_in[2];
    const float* W1  = (const float*)d_in[3];
    const float* b1  = (const float*)d_in[4];
    const float* W2  = (const float*)d_in[5];
    const float* b2  = (const float*)d_in[6];
    const float* W3  = (const float*)d_in[7];
    const float* b3  = (const float*)d_in[8];
    const float* Wl  = (const float*)d_in[9];
    const float* bl  = (const float*)d_in[10];
    float* out = (float*)d_out;

    char* p = (char*)d_ws;
    auto alloc = [&](size_t bytes) -> void* {
        void* r = (void*)p;
        p += (bytes + 255) & ~(size_t)255;
        return r;
    };
    int*   ghist   = (int*)alloc((size_t)NBIN * 4);
    int*   binbase = (int*)alloc((size_t)(NBIN + 1) * 4);
    int*   gcur    = (int*)alloc((size_t)NBIN * 4);
    int*   rp4     = (int*)alloc((size_t)NBIN * 209 * 4);
    float* dinv    = (float*)alloc((size_t)N_NODES * 4);
    int*   colb    = (int*)alloc((size_t)N_EDGES * 4);
    int*   ebuf    = (int*)alloc((size_t)N_EDGES * 4);
    float* u1      = (float*)alloc((size_t)N_NODES * D_H * 4);
    float* u2      = (float*)alloc((size_t)N_NODES * D_H * 4);
    float* h       = (float*)alloc((size_t)N_NODES * D_H * 4);
    float* val     = (float*)alloc((size_t)N_NODES * 4);

    hipMemsetAsync(ghist, 0, (size_t)NBIN * 4, stream);

    const int* srcp = ei;
    const int* dstp = ei + N_EDGES;

    int gbl = (N_NODES + 63) / 64;

    // CSR build (group/bucket-major per-bin sort, rp4 boundaries)
    k_hist<<<HIST_BLOCKS, 256, 0, stream>>>(dstp, ghist);
    k_scanbins<<<1, 512, 0, stream>>>(ghist, binbase, gcur);
    k_part<<<PART_BLOCKS, 256, 0, stream>>>(srcp, dstp, gcur, ebuf);
    k_sortbin<<<NBIN, 256, 0, stream>>>(binbase, ebuf, colb, rp4, dinv);

    // layer 1: 320 -> 64
    k_gemm<D_IN><<<gbl, 256, 0, stream>>>(x, W1, dinv, u1);
    k_aggb<<<NBIN * 4, 256, 0, stream>>>(u1, rp4, colb, dinv, b1, h);
    // layer 2: 64 -> 64
    k_gemm<D_H><<<gbl, 256, 0, stream>>>(h, W2, dinv, u2);
    k_aggb<<<NBIN * 4, 256, 0, stream>>>(u2, rp4, colb, dinv, b2, h);
    // layer 3: 64 -> 64, fused with linear head dot
    k_gemm<D_H><<<gbl, 256, 0, stream>>>(h, W3, dinv, u1);
    k_aggb_dot<<<NBIN * 4, 256, 0, stream>>>(u1, rp4, colb, dinv, b3, Wl, val);

    // pooling
    k_gpool<<<N_GRAPHS, 256, 0, stream>>>(val, bat, bl, out);
}

// Round 11
// 471.204 us; speedup vs baseline: 7.9980x; 7.9980x over previous
//
#include <hip/hip_runtime.h>
#include <hip/hip_bf16.h>
#include <hip/hip_fp16.h>

#define N_NODES 100000
#define N_EDGES 3200000
#define N_GRAPHS 256
#define D_IN 320
#define D_H 64

#define NBIN 391                    // ceil(N_NODES / 256) bins of 256 dst nodes
#define BIN_CAP 12288               // mean bin load 8186, sigma~90 -> +45 sigma
#define HIST_BLOCKS 256
#define HIST_CHUNK ((N_EDGES + HIST_BLOCKS - 1) / HIST_BLOCKS)
#define PART_BLOCKS 200
#define PART_CHUNK ((N_EDGES + PART_BLOCKS - 1) / PART_BLOCKS)   // 16000

// ---------------- CSR build (block-private chunk partition) ----------------

__global__ __launch_bounds__(256) void k_hist(const int* __restrict__ dst,
                                              int* __restrict__ ghist) {
    __shared__ int lh[NBIN];
    for (int i = threadIdx.x; i < NBIN; i += 256) lh[i] = 0;
    __syncthreads();
    int beg = blockIdx.x * HIST_CHUNK;
    int end = min(beg + HIST_CHUNK, N_EDGES);
    for (int e = beg + threadIdx.x; e < end; e += 256)
        atomicAdd(&lh[dst[e] >> 8], 1);
    __syncthreads();
    for (int i = threadIdx.x; i < NBIN; i += 256)
        if (lh[i]) atomicAdd(&ghist[i], lh[i]);
}

__global__ __launch_bounds__(512) void k_scanbins(const int* __restrict__ ghist,
                                                  int* __restrict__ binbase,
                                                  int* __restrict__ gcur,
                                                  int* __restrict__ rowptr) {
    __shared__ int sa[512], sb[512];
    int t = threadIdx.x;
    int v = (t < NBIN) ? ghist[t] : 0;
    sa[t] = v;
    __syncthreads();
    int* in = sa; int* out = sb;
    for (int off = 1; off < 512; off <<= 1) {
        out[t] = in[t] + (t >= off ? in[t - off] : 0);
        __syncthreads();
        int* tmp = in; in = out; out = tmp;
    }
    int excl = in[t] - v;
    if (t < NBIN) { binbase[t] = excl; gcur[t] = excl; }
    if (t == 511) { binbase[NBIN] = in[511]; rowptr[N_NODES] = in[511]; }
}

// partition edges into 391 bins; each block reserves a private contiguous
// chunk per bin (one global atomic per (block,bin)) -> every ebuf cacheline
// is written by exactly one block, once.
__global__ __launch_bounds__(256) void k_part(const int* __restrict__ src,
                                              const int* __restrict__ dst,
                                              int* __restrict__ gcur,
                                              int* __restrict__ ebuf) {
    __shared__ int lh[NBIN], gb[NBIN], cur[NBIN];
    for (int i = threadIdx.x; i < NBIN; i += 256) { lh[i] = 0; cur[i] = 0; }
    __syncthreads();
    int beg = blockIdx.x * PART_CHUNK;
    int end = min(beg + PART_CHUNK, N_EDGES);
    for (int e = beg + threadIdx.x; e < end; e += 256)
        atomicAdd(&lh[dst[e] >> 8], 1);
    __syncthreads();
    for (int i = threadIdx.x; i < NBIN; i += 256)
        gb[i] = lh[i] ? atomicAdd(&gcur[i], lh[i]) : 0;
    __syncthreads();
    for (int e = beg + threadIdx.x; e < end; e += 256) {
        int d = dst[e], s = src[e];
        int bin = d >> 8;
        int r = atomicAdd(&cur[bin], 1);
        ebuf[gb[bin] + r] = ((d & 255) << 17) | s;   // dst-low-8 | src(17b)
    }
}

// one block per bin: LDS counting-sort by dst; writes col coalesced and
// emits rowptr + dinv for its 256 nodes.
__global__ __launch_bounds__(256) void k_sortbin(const int* __restrict__ binbase,
                                                 const int* __restrict__ ebuf,
                                                 int* __restrict__ col,
                                                 int* __restrict__ rowptr,
                                                 float* __restrict__ dinv) {
    __shared__ int hc[256], sc[256], sa[256], sb[256];
    __shared__ int scol[BIN_CAP];
    int b = blockIdx.x, t = threadIdx.x;
    int d0 = b << 8;
    int e0 = binbase[b], e1 = binbase[b + 1];
    hc[t] = 0;
    __syncthreads();
    for (int i = e0 + t; i < e1; i += 256)
        atomicAdd(&hc[ebuf[i] >> 17], 1);
    __syncthreads();
    sa[t] = hc[t];
    __syncthreads();
    int* in = sa; int* out = sb;
    for (int o = 1; o < 256; o <<= 1) {
        out[t] = in[t] + (t >= o ? in[t - o] : 0);
        __syncthreads();
        int* tm = in; in = out; out = tm;
    }
    int excl = in[t] - hc[t];
    sc[t] = excl;
    int node = d0 + t;
    if (node < N_NODES) {
        rowptr[node] = e0 + excl;
        dinv[node] = rsqrtf((float)(hc[t] + 1));   // +1 self loop
    }
    __syncthreads();
    for (int i = e0 + t; i < e1; i += 256) {
        int pk = ebuf[i];
        int p = atomicAdd(&sc[pk >> 17], 1);
        if (p < BIN_CAP) scol[p] = pk & 0x1FFFF;
    }
    __syncthreads();
    int n = e1 - e0;
    for (int i = t; i < n; i += 256) col[e0 + i] = scol[i];
}

// ---------------- tiled GEMM transform ----------------
// u[node][f] = half( (A[node,:] @ W)[f] * dinv[node] )
template<int K>
__global__ __launch_bounds__(256) void k_gemm(const float* __restrict__ A,
                                              const float* __restrict__ W,
                                              const float* __restrict__ dinv,
                                              __half* __restrict__ u) {
    __shared__ __align__(16) float xt[64][68];
    __shared__ __align__(16) float ws[64][68];
    int t = threadIdx.x;
    int ti = t & 15;
    int tj = t >> 4;
    int node0 = blockIdx.x * 64;
    float acc[4][4] = {{0.f}};

    for (int kc = 0; kc < K; kc += 64) {
        if (kc) __syncthreads();
#pragma unroll
        for (int p = 0; p < 4; ++p) {
            int m = tj + 16 * p;
            int node = node0 + m;
            if (node >= N_NODES) node = N_NODES - 1;
            float4 v = *(const float4*)(A + (size_t)node * K + kc + 4 * ti);
            xt[4 * ti + 0][m] = v.x;
            xt[4 * ti + 1][m] = v.y;
            xt[4 * ti + 2][m] = v.z;
            xt[4 * ti + 3][m] = v.w;
            float4 wv = *(const float4*)(W + (size_t)(kc + m) * D_H + 4 * ti);
            *(float4*)&ws[m][4 * ti] = wv;
        }
        __syncthreads();
#pragma unroll 16
        for (int k = 0; k < 64; ++k) {
            float4 xv = *(const float4*)&xt[k][4 * tj];
            float4 wv = *(const float4*)&ws[k][4 * ti];
            float xa[4] = {xv.x, xv.y, xv.z, xv.w};
            float wa[4] = {wv.x, wv.y, wv.z, wv.w};
#pragma unroll
            for (int i = 0; i < 4; ++i)
#pragma unroll
                for (int j = 0; j < 4; ++j)
                    acc[i][j] = fmaf(xa[i], wa[j], acc[i][j]);
        }
    }
#pragma unroll
    for (int i = 0; i < 4; ++i) {
        int node = node0 + 4 * tj + i;
        if (node < N_NODES) {
            float dv = dinv[node];
            __half2* up = (__half2*)(u + (size_t)node * D_H + 4 * ti);
            up[0] = __floats2half2_rn(acc[i][0] * dv, acc[i][1] * dv);
            up[1] = __floats2half2_rn(acc[i][2] * dv, acc[i][3] * dv);
        }
    }
}

// ---------------- aggregation (one wave per node, 8-deep gathers) ----------

__device__ __forceinline__ float agg_gather(const __half* __restrict__ u,
                                            const int* __restrict__ col,
                                            int beg, int end, int lane, float acc) {
    int e = beg;
    for (; e + 7 < end; e += 8) {                // 8 independent gathers in flight
        int s0 = col[e],     s1 = col[e + 1], s2 = col[e + 2], s3 = col[e + 3];
        int s4 = col[e + 4], s5 = col[e + 5], s6 = col[e + 6], s7 = col[e + 7];
        __half v0 = u[(size_t)s0 * D_H + lane];
        __half v1 = u[(size_t)s1 * D_H + lane];
        __half v2 = u[(size_t)s2 * D_H + lane];
        __half v3 = u[(size_t)s3 * D_H + lane];
        __half v4 = u[(size_t)s4 * D_H + lane];
        __half v5 = u[(size_t)s5 * D_H + lane];
        __half v6 = u[(size_t)s6 * D_H + lane];
        __half v7 = u[(size_t)s7 * D_H + lane];
        acc += ((__half2float(v0) + __half2float(v1)) +
                (__half2float(v2) + __half2float(v3))) +
               ((__half2float(v4) + __half2float(v5)) +
                (__half2float(v6) + __half2float(v7)));
    }
    for (; e < end; ++e) acc += __half2float(u[(size_t)col[e] * D_H + lane]);
    return acc;
}

// h[i] = relu( dinv[i] * (sum_{src in N(i)} u[src] + u[i]) + b )
__global__ __launch_bounds__(256) void k_agg(const __half* __restrict__ u,
                                             const int* __restrict__ rowptr,
                                             const int* __restrict__ col,
                                             const float* __restrict__ dinv,
                                             const float* __restrict__ b,
                                             float* __restrict__ h) {
    int lane = threadIdx.x & 63;
    int node = (blockIdx.x * blockDim.x + threadIdx.x) >> 6;
    if (node >= N_NODES) return;
    float acc = __half2float(u[(size_t)node * D_H + lane]);    // self loop
    acc = agg_gather(u, col, rowptr[node], rowptr[node + 1], lane, acc);
    acc = acc * dinv[node] + b[lane];
    h[(size_t)node * D_H + lane] = fmaxf(acc, 0.0f);
}

// layer 3 fused with the linear head: val[i] = dot(agg_row + b3, Wl)
__global__ __launch_bounds__(256) void k_agg_dot(const __half* __restrict__ uin,
                                                 const int* __restrict__ rowptr,
                                                 const int* __restrict__ col,
                                                 const float* __restrict__ dinv,
                                                 const float* __restrict__ b,
                                                 const float* __restrict__ Wl,
                                                 float* __restrict__ val) {
    int lane = threadIdx.x & 63;
    int node = (blockIdx.x * blockDim.x + threadIdx.x) >> 6;
    if (node >= N_NODES) return;
    float acc = __half2float(uin[(size_t)node * D_H + lane]);    // self loop
    acc = agg_gather(uin, col, rowptr[node], rowptr[node + 1], lane, acc);
    acc = acc * dinv[node] + b[lane];
    float v = acc * Wl[lane];
#pragma unroll
    for (int m = 32; m > 0; m >>= 1) v += __shfl_xor(v, m, 64);
    if (lane == 0) val[node] = v;
}

// one block per graph: batch is sorted, binary-search the segment, reduce.
__global__ __launch_bounds__(256) void k_gpool(const float* __restrict__ val,
                                               const int* __restrict__ batch,
                                               const float* __restrict__ bl,
                                               float* __restrict__ out) {
    int g = blockIdx.x;
    int l = 0, r = N_NODES;
    while (l < r) { int m = (l + r) >> 1; if (batch[m] < g) l = m + 1; else r = m; }
    int lo = l;
    r = N_NODES;
    while (l < r) { int m = (l + r) >> 1; if (batch[m] < g + 1) l = m + 1; else r = m; }
    int hi = l;
    float s = 0.0f;
    for (int i = lo + threadIdx.x; i < hi; i += 256) s += val[i];
#pragma unroll
    for (int m = 32; m > 0; m >>= 1) s += __shfl_xor(s, m, 64);
    __shared__ float red[4];
    int wid = threadIdx.x >> 6, lane = threadIdx.x & 63;
    if (lane == 0) red[wid] = s;
    __syncthreads();
    if (threadIdx.x == 0) {
        float t = red[0] + red[1] + red[2] + red[3];
        out[g] = t / fmaxf((float)(hi - lo), 1.0f) + bl[0];
    }
}

// ---------------- launch ----------------

extern "C" void kernel_launch(void* const* d_in, const int* in_sizes, int n_in,
                              void* d_out, int out_size, void* d_ws, size_t ws_size,
                              hipStream_t stream) {
    const float* x   = (const float*)d_in[0];
    const int*   ei  = (const int*)d_in[1];
    const int*   bat = (const int*)d_in[2];
    const float* W1  = (const float*)d_in[3];
    const float* b1  = (const float*)d_in[4];
    const float* W2  = (const float*)d_in[5];
    const float* b2  = (const float*)d_in[6];
    const float* W3  = (const float*)d_in[7];
    const float* b3  = (const float*)d_in[8];
    const float* Wl  = (const float*)d_in[9];
    const float* bl  = (const float*)d_in[10];
    float* out = (float*)d_out;

    char* p = (char*)d_ws;
    auto alloc = [&](size_t bytes) -> void* {
        void* r = (void*)p;
        p += (bytes + 255) & ~(size_t)255;
        return r;
    };
    int*    ghist   = (int*)alloc((size_t)NBIN * 4);
    int*    binbase = (int*)alloc((size_t)(NBIN + 1) * 4);
    int*    gcur    = (int*)alloc((size_t)NBIN * 4);
    int*    rowptr  = (int*)alloc((size_t)(N_NODES + 1) * 4);
    float*  dinv    = (float*)alloc((size_t)N_NODES * 4);
    int*    colb    = (int*)alloc((size_t)N_EDGES * 4);
    int*    ebuf    = (int*)alloc((size_t)N_EDGES * 4);
    __half* u1      = (__half*)alloc((size_t)N_NODES * D_H * 2);
    __half* u2      = (__half*)alloc((size_t)N_NODES * D_H * 2);
    float*  h       = (float*)alloc((size_t)N_NODES * D_H * 4);
    float*  val     = (float*)alloc((size_t)N_NODES * 4);

    hipMemsetAsync(ghist, 0, (size_t)NBIN * 4, stream);

    const int* srcp = ei;
    const int* dstp = ei + N_EDGES;

    int wbl = (N_NODES * 64 + 255) / 256;           // one wave per node
    int gbl = (N_NODES + 63) / 64;

    // CSR build
    k_hist<<<HIST_BLOCKS, 256, 0, stream>>>(dstp, ghist);
    k_scanbins<<<1, 512, 0, stream>>>(ghist, binbase, gcur, rowptr);
    k_part<<<PART_BLOCKS, 256, 0, stream>>>(srcp, dstp, gcur, ebuf);
    k_sortbin<<<NBIN, 256, 0, stream>>>(binbase, ebuf, colb, rowptr, dinv);

    // layer 1: 320 -> 64
    k_gemm<D_IN><<<gbl, 256, 0, stream>>>(x, W1, dinv, u1);
    k_agg<<<wbl, 256, 0, stream>>>(u1, rowptr, colb, dinv, b1, h);
    // layer 2: 64 -> 64
    k_gemm<D_H><<<gbl, 256, 0, stream>>>(h, W2, dinv, u2);
    k_agg<<<wbl, 256, 0, stream>>>(u2, rowptr, colb, dinv, b2, h);
    // layer 3: 64 -> 64, fused with linear head dot
    k_gemm<D_H><<<gbl, 256, 0, stream>>>(h, W3, dinv, u1);
    k_agg_dot<<<wbl, 256, 0, stream>>>(u1, rowptr, colb, dinv, b3, Wl, val);

    // pooling
    k_gpool<<<N_GRAPHS, 256, 0, stream>>>(val, bat, bl, out);
}

// Round 12
// 439.485 us; speedup vs baseline: 8.5752x; 1.0722x over previous
//
#include <hip/hip_runtime.h>
#include <hip/hip_bf16.h>
#include <hip/hip_fp16.h>

#define N_NODES 100000
#define N_EDGES 3200000
#define N_GRAPHS 256
#define D_IN 320
#define D_H 64

#define NBIN 391                    // ceil(N_NODES / 256) bins of 256 dst nodes
#define BIN_CAP 12288               // mean bin load 8186, sigma~90 -> +45 sigma
#define HIST_BLOCKS 256
#define HIST_CHUNK ((N_EDGES + HIST_BLOCKS - 1) / HIST_BLOCKS)
#define PART_BLOCKS 200
#define PART_CHUNK ((N_EDGES + PART_BLOCKS - 1) / PART_BLOCKS)   // 16000

// ---------------- CSR build (block-private chunk partition) ----------------

__global__ __launch_bounds__(256) void k_hist(const int* __restrict__ dst,
                                              int* __restrict__ ghist) {
    __shared__ int lh[NBIN];
    for (int i = threadIdx.x; i < NBIN; i += 256) lh[i] = 0;
    __syncthreads();
    int beg = blockIdx.x * HIST_CHUNK;
    int end = min(beg + HIST_CHUNK, N_EDGES);
    for (int e = beg + threadIdx.x; e < end; e += 256)
        atomicAdd(&lh[dst[e] >> 8], 1);
    __syncthreads();
    for (int i = threadIdx.x; i < NBIN; i += 256)
        if (lh[i]) atomicAdd(&ghist[i], lh[i]);
}

__global__ __launch_bounds__(512) void k_scanbins(const int* __restrict__ ghist,
                                                  int* __restrict__ binbase,
                                                  int* __restrict__ gcur,
                                                  int* __restrict__ rowptr) {
    __shared__ int sa[512], sb[512];
    int t = threadIdx.x;
    int v = (t < NBIN) ? ghist[t] : 0;
    sa[t] = v;
    __syncthreads();
    int* in = sa; int* out = sb;
    for (int off = 1; off < 512; off <<= 1) {
        out[t] = in[t] + (t >= off ? in[t - off] : 0);
        __syncthreads();
        int* tmp = in; in = out; out = tmp;
    }
    int excl = in[t] - v;
    if (t < NBIN) { binbase[t] = excl; gcur[t] = excl; }
    if (t == 511) { binbase[NBIN] = in[511]; rowptr[N_NODES] = in[511]; }
}

// partition edges into 391 bins; each block reserves a private contiguous
// chunk per bin (one global atomic per (block,bin)) -> every ebuf cacheline
// is written by exactly one block, once.
__global__ __launch_bounds__(256) void k_part(const int* __restrict__ src,
                                              const int* __restrict__ dst,
                                              int* __restrict__ gcur,
                                              int* __restrict__ ebuf) {
    __shared__ int lh[NBIN], gb[NBIN], cur[NBIN];
    for (int i = threadIdx.x; i < NBIN; i += 256) { lh[i] = 0; cur[i] = 0; }
    __syncthreads();
    int beg = blockIdx.x * PART_CHUNK;
    int end = min(beg + PART_CHUNK, N_EDGES);
    for (int e = beg + threadIdx.x; e < end; e += 256)
        atomicAdd(&lh[dst[e] >> 8], 1);
    __syncthreads();
    for (int i = threadIdx.x; i < NBIN; i += 256)
        gb[i] = lh[i] ? atomicAdd(&gcur[i], lh[i]) : 0;
    __syncthreads();
    for (int e = beg + threadIdx.x; e < end; e += 256) {
        int d = dst[e], s = src[e];
        int bin = d >> 8;
        int r = atomicAdd(&cur[bin], 1);
        ebuf[gb[bin] + r] = ((d & 255) << 17) | s;   // dst-low-8 | src(17b)
    }
}

// one block per bin: LDS counting-sort by dst; writes col coalesced and
// emits rowptr + dinv for its 256 nodes.
__global__ __launch_bounds__(256) void k_sortbin(const int* __restrict__ binbase,
                                                 const int* __restrict__ ebuf,
                                                 int* __restrict__ col,
                                                 int* __restrict__ rowptr,
                                                 float* __restrict__ dinv) {
    __shared__ int hc[256], sc[256], sa[256], sb[256];
    __shared__ int scol[BIN_CAP];
    int b = blockIdx.x, t = threadIdx.x;
    int d0 = b << 8;
    int e0 = binbase[b], e1 = binbase[b + 1];
    hc[t] = 0;
    __syncthreads();
    for (int i = e0 + t; i < e1; i += 256)
        atomicAdd(&hc[ebuf[i] >> 17], 1);
    __syncthreads();
    sa[t] = hc[t];
    __syncthreads();
    int* in = sa; int* out = sb;
    for (int o = 1; o < 256; o <<= 1) {
        out[t] = in[t] + (t >= o ? in[t - o] : 0);
        __syncthreads();
        int* tm = in; in = out; out = tm;
    }
    int excl = in[t] - hc[t];
    sc[t] = excl;
    int node = d0 + t;
    if (node < N_NODES) {
        rowptr[node] = e0 + excl;
        dinv[node] = rsqrtf((float)(hc[t] + 1));   // +1 self loop
    }
    __syncthreads();
    for (int i = e0 + t; i < e1; i += 256) {
        int pk = ebuf[i];
        int p = atomicAdd(&sc[pk >> 17], 1);
        if (p < BIN_CAP) scol[p] = pk & 0x1FFFF;
    }
    __syncthreads();
    int n = e1 - e0;
    for (int i = t; i < n; i += 256) col[e0 + i] = scol[i];
}

// ---------------- tiled GEMM transform ----------------
// u[node][f] = half( (A[node,:] @ W)[f] * dinv[node] )
template<int K>
__global__ __launch_bounds__(256) void k_gemm(const float* __restrict__ A,
                                              const float* __restrict__ W,
                                              const float* __restrict__ dinv,
                                              __half* __restrict__ u) {
    __shared__ __align__(16) float xt[64][68];
    __shared__ __align__(16) float ws[64][68];
    int t = threadIdx.x;
    int ti = t & 15;
    int tj = t >> 4;
    int node0 = blockIdx.x * 64;
    float acc[4][4] = {{0.f}};

    for (int kc = 0; kc < K; kc += 64) {
        if (kc) __syncthreads();
#pragma unroll
        for (int p = 0; p < 4; ++p) {
            int m = tj + 16 * p;
            int node = node0 + m;
            if (node >= N_NODES) node = N_NODES - 1;
            float4 v = *(const float4*)(A + (size_t)node * K + kc + 4 * ti);
            xt[4 * ti + 0][m] = v.x;
            xt[4 * ti + 1][m] = v.y;
            xt[4 * ti + 2][m] = v.z;
            xt[4 * ti + 3][m] = v.w;
            float4 wv = *(const float4*)(W + (size_t)(kc + m) * D_H + 4 * ti);
            *(float4*)&ws[m][4 * ti] = wv;
        }
        __syncthreads();
#pragma unroll 16
        for (int k = 0; k < 64; ++k) {
            float4 xv = *(const float4*)&xt[k][4 * tj];
            float4 wv = *(const float4*)&ws[k][4 * ti];
            float xa[4] = {xv.x, xv.y, xv.z, xv.w};
            float wa[4] = {wv.x, wv.y, wv.z, wv.w};
#pragma unroll
            for (int i = 0; i < 4; ++i)
#pragma unroll
                for (int j = 0; j < 4; ++j)
                    acc[i][j] = fmaf(xa[i], wa[j], acc[i][j]);
        }
    }
#pragma unroll
    for (int i = 0; i < 4; ++i) {
        int node = node0 + 4 * tj + i;
        if (node < N_NODES) {
            float dv = dinv[node];
            __half2* up = (__half2*)(u + (size_t)node * D_H + 4 * ti);
            up[0] = __floats2half2_rn(acc[i][0] * dv, acc[i][1] * dv);
            up[1] = __floats2half2_rn(acc[i][2] * dv, acc[i][3] * dv);
        }
    }
}

// ------------- aggregation: 4 edges/wave, 8 B/lane, 8-deep pipeline -------
// Wave = 4 sub-waves of 16 lanes. Sub-wave q handles edges e = beg+q (mod 4);
// lane fq covers features 4fq..4fq+3 (uint2 = 4 halves). One instruction
// gathers 4 full 128 B rows.

__device__ __forceinline__ void acc4(float4& a, uint2 w) {
    __half2 h0 = *reinterpret_cast<__half2*>(&w.x);
    __half2 h1 = *reinterpret_cast<__half2*>(&w.y);
    float2 f0 = __half22float2(h0);
    float2 f1 = __half22float2(h1);
    a.x += f0.x; a.y += f0.y; a.z += f1.x; a.w += f1.y;
}

__device__ __forceinline__ float4 agg_gather4(const __half* __restrict__ u,
                                              const int* __restrict__ col,
                                              int beg, int end, int q, int fq) {
    float4 acc = make_float4(0.f, 0.f, 0.f, 0.f);
    int base = beg;
    for (; base + 31 < end; base += 32) {        // 32 edges/iter, 8 per sub-wave
        int e = base + q;
        int s0 = col[e],      s1 = col[e + 4],  s2 = col[e + 8],  s3 = col[e + 12];
        int s4 = col[e + 16], s5 = col[e + 20], s6 = col[e + 24], s7 = col[e + 28];
        uint2 w0 = *(const uint2*)(u + (size_t)s0 * D_H + fq * 4);
        uint2 w1 = *(const uint2*)(u + (size_t)s1 * D_H + fq * 4);
        uint2 w2 = *(const uint2*)(u + (size_t)s2 * D_H + fq * 4);
        uint2 w3 = *(const uint2*)(u + (size_t)s3 * D_H + fq * 4);
        uint2 w4 = *(const uint2*)(u + (size_t)s4 * D_H + fq * 4);
        uint2 w5 = *(const uint2*)(u + (size_t)s5 * D_H + fq * 4);
        uint2 w6 = *(const uint2*)(u + (size_t)s6 * D_H + fq * 4);
        uint2 w7 = *(const uint2*)(u + (size_t)s7 * D_H + fq * 4);
        acc4(acc, w0); acc4(acc, w1); acc4(acc, w2); acc4(acc, w3);
        acc4(acc, w4); acc4(acc, w5); acc4(acc, w6); acc4(acc, w7);
    }
    for (int e = base + q; e < end; e += 4) {    // remainder (divergent, <=8 iters)
        uint2 w = *(const uint2*)(u + (size_t)col[e] * D_H + fq * 4);
        acc4(acc, w);
    }
    return acc;
}

// h[i] = relu( dinv[i] * (sum u[src] + u[i]) + b )
__global__ __launch_bounds__(256) void k_agg(const __half* __restrict__ u,
                                             const int* __restrict__ rowptr,
                                             const int* __restrict__ col,
                                             const float* __restrict__ dinv,
                                             const float* __restrict__ b,
                                             float* __restrict__ h) {
    int t = threadIdx.x;
    int lane = t & 63, q = lane >> 4, fq = lane & 15;
    int node = (blockIdx.x * blockDim.x + t) >> 6;
    if (node >= N_NODES) return;
    float4 acc = agg_gather4(u, col, rowptr[node], rowptr[node + 1], q, fq);
    if (q == 0) {                                // self loop, counted once
        uint2 w = *(const uint2*)(u + (size_t)node * D_H + fq * 4);
        acc4(acc, w);
    }
    // combine the 4 sub-waves (lanes share fq)
    acc.x += __shfl_xor(acc.x, 16, 64); acc.y += __shfl_xor(acc.y, 16, 64);
    acc.z += __shfl_xor(acc.z, 16, 64); acc.w += __shfl_xor(acc.w, 16, 64);
    acc.x += __shfl_xor(acc.x, 32, 64); acc.y += __shfl_xor(acc.y, 32, 64);
    acc.z += __shfl_xor(acc.z, 32, 64); acc.w += __shfl_xor(acc.w, 32, 64);
    if (q == 0) {
        float dv = dinv[node];
        float4 bb = *(const float4*)(b + 4 * fq);
        float4 o;
        o.x = fmaxf(acc.x * dv + bb.x, 0.f);
        o.y = fmaxf(acc.y * dv + bb.y, 0.f);
        o.z = fmaxf(acc.z * dv + bb.z, 0.f);
        o.w = fmaxf(acc.w * dv + bb.w, 0.f);
        *(float4*)(h + (size_t)node * D_H + 4 * fq) = o;
    }
}

// layer 3 + head: val[i] = dot(agg_row*dinv + b, Wl)
__global__ __launch_bounds__(256) void k_agg_dot(const __half* __restrict__ uin,
                                                 const int* __restrict__ rowptr,
                                                 const int* __restrict__ col,
                                                 const float* __restrict__ dinv,
                                                 const float* __restrict__ b,
                                                 const float* __restrict__ Wl,
                                                 float* __restrict__ val) {
    int t = threadIdx.x;
    int lane = t & 63, q = lane >> 4, fq = lane & 15;
    int node = (blockIdx.x * blockDim.x + t) >> 6;
    if (node >= N_NODES) return;
    float4 acc = agg_gather4(uin, col, rowptr[node], rowptr[node + 1], q, fq);
    if (q == 0) {                                // self loop, counted once
        uint2 w = *(const uint2*)(uin + (size_t)node * D_H + fq * 4);
        acc4(acc, w);
    }
    float4 wl = *(const float4*)(Wl + 4 * fq);
    float dv = dinv[node];
    float v = dv * (acc.x * wl.x + acc.y * wl.y + acc.z * wl.z + acc.w * wl.w);
    if (q == 0) {                                // bias term, counted once
        float4 bb = *(const float4*)(b + 4 * fq);
        v += bb.x * wl.x + bb.y * wl.y + bb.z * wl.z + bb.w * wl.w;
    }
#pragma unroll
    for (int m = 32; m > 0; m >>= 1) v += __shfl_xor(v, m, 64);
    if (lane == 0) val[node] = v;
}

// one block per graph: batch is sorted, binary-search the segment, reduce.
__global__ __launch_bounds__(256) void k_gpool(const float* __restrict__ val,
                                               const int* __restrict__ batch,
                                               const float* __restrict__ bl,
                                               float* __restrict__ out) {
    int g = blockIdx.x;
    int l = 0, r = N_NODES;
    while (l < r) { int m = (l + r) >> 1; if (batch[m] < g) l = m + 1; else r = m; }
    int lo = l;
    r = N_NODES;
    while (l < r) { int m = (l + r) >> 1; if (batch[m] < g + 1) l = m + 1; else r = m; }
    int hi = l;
    float s = 0.0f;
    for (int i = lo + threadIdx.x; i < hi; i += 256) s += val[i];
#pragma unroll
    for (int m = 32; m > 0; m >>= 1) s += __shfl_xor(s, m, 64);
    __shared__ float red[4];
    int wid = threadIdx.x >> 6, lane = threadIdx.x & 63;
    if (lane == 0) red[wid] = s;
    __syncthreads();
    if (threadIdx.x == 0) {
        float t = red[0] + red[1] + red[2] + red[3];
        out[g] = t / fmaxf((float)(hi - lo), 1.0f) + bl[0];
    }
}

// ---------------- launch ----------------

extern "C" void kernel_launch(void* const* d_in, const int* in_sizes, int n_in,
                              void* d_out, int out_size, void* d_ws, size_t ws_size,
                              hipStream_t stream) {
    const float* x   = (const float*)d_in[0];
    const int*   ei  = (const int*)d_in[1];
    const int*   bat = (const int*)d_in[2];
    const float* W1  = (const float*)d_in[3];
    const float* b1  = (const float*)d_in[4];
    const float* W2  = (const float*)d_in[5];
    const float* b2  = (const float*)d_in[6];
    const float* W3  = (const float*)d_in[7];
    const float* b3  = (const float*)d_in[8];
    const float* Wl  = (const float*)d_in[9];
    const float* bl  = (const float*)d_in[10];
    float* out = (float*)d_out;

    char* p = (char*)d_ws;
    auto alloc = [&](size_t bytes) -> void* {
        void* r = (void*)p;
        p += (bytes + 255) & ~(size_t)255;
        return r;
    };
    int*    ghist   = (int*)alloc((size_t)NBIN * 4);
    int*    binbase = (int*)alloc((size_t)(NBIN + 1) * 4);
    int*    gcur    = (int*)alloc((size_t)NBIN * 4);
    int*    rowptr  = (int*)alloc((size_t)(N_NODES + 1) * 4);
    float*  dinv    = (float*)alloc((size_t)N_NODES * 4);
    int*    colb    = (int*)alloc((size_t)N_EDGES * 4);
    int*    ebuf    = (int*)alloc((size_t)N_EDGES * 4);
    __half* u1      = (__half*)alloc((size_t)N_NODES * D_H * 2);
    __half* u2      = (__half*)alloc((size_t)N_NODES * D_H * 2);
    float*  h       = (float*)alloc((size_t)N_NODES * D_H * 4);
    float*  val     = (float*)alloc((size_t)N_NODES * 4);

    hipMemsetAsync(ghist, 0, (size_t)NBIN * 4, stream);

    const int* srcp = ei;
    const int* dstp = ei + N_EDGES;

    int wbl = (N_NODES * 64 + 255) / 256;           // one wave per node
    int gbl = (N_NODES + 63) / 64;

    // CSR build
    k_hist<<<HIST_BLOCKS, 256, 0, stream>>>(dstp, ghist);
    k_scanbins<<<1, 512, 0, stream>>>(ghist, binbase, gcur, rowptr);
    k_part<<<PART_BLOCKS, 256, 0, stream>>>(srcp, dstp, gcur, ebuf);
    k_sortbin<<<NBIN, 256, 0, stream>>>(binbase, ebuf, colb, rowptr, dinv);

    // layer 1: 320 -> 64
    k_gemm<D_IN><<<gbl, 256, 0, stream>>>(x, W1, dinv, u1);
    k_agg<<<wbl, 256, 0, stream>>>(u1, rowptr, colb, dinv, b1, h);
    // layer 2: 64 -> 64
    k_gemm<D_H><<<gbl, 256, 0, stream>>>(h, W2, dinv, u2);
    k_agg<<<wbl, 256, 0, stream>>>(u2, rowptr, colb, dinv, b2, h);
    // layer 3: 64 -> 64, fused with linear head dot
    k_gemm<D_H><<<gbl, 256, 0, stream>>>(h, W3, dinv, u1);
    k_agg_dot<<<wbl, 256, 0, stream>>>(u1, rowptr, colb, dinv, b3, Wl, val);

    // pooling
    k_gpool<<<N_GRAPHS, 256, 0, stream>>>(val, bat, bl, out);
}

// Round 13
// 433.154 us; speedup vs baseline: 8.7006x; 1.0146x over previous
//
#include <hip/hip_runtime.h>
#include <hip/hip_bf16.h>
#include <hip/hip_fp16.h>

#define N_NODES 100000
#define N_EDGES 3200000
#define N_GRAPHS 256
#define D_IN 320
#define D_H 64

#define NBIN 391                    // ceil(N_NODES / 256) bins of 256 dst nodes
#define BIN_CAP 12288               // mean bin load 8186, sigma~90 -> +45 sigma
#define HIST_BLOCKS 256
#define HIST_CHUNK ((N_EDGES + HIST_BLOCKS - 1) / HIST_BLOCKS)
#define PART_BLOCKS 200
#define PART_CHUNK ((N_EDGES + PART_BLOCKS - 1) / PART_BLOCKS)   // 16000

// ---------------- CSR build (block-private chunk partition) ----------------

__global__ __launch_bounds__(256) void k_hist(const int* __restrict__ dst,
                                              int* __restrict__ ghist) {
    __shared__ int lh[NBIN];
    for (int i = threadIdx.x; i < NBIN; i += 256) lh[i] = 0;
    __syncthreads();
    int beg = blockIdx.x * HIST_CHUNK;
    int end = min(beg + HIST_CHUNK, N_EDGES);
    for (int e = beg + threadIdx.x; e < end; e += 256)
        atomicAdd(&lh[dst[e] >> 8], 1);
    __syncthreads();
    for (int i = threadIdx.x; i < NBIN; i += 256)
        if (lh[i]) atomicAdd(&ghist[i], lh[i]);
}

__global__ __launch_bounds__(512) void k_scanbins(const int* __restrict__ ghist,
                                                  int* __restrict__ binbase,
                                                  int* __restrict__ gcur,
                                                  int* __restrict__ rowptr) {
    __shared__ int sa[512], sb[512];
    int t = threadIdx.x;
    int v = (t < NBIN) ? ghist[t] : 0;
    sa[t] = v;
    __syncthreads();
    int* in = sa; int* out = sb;
    for (int off = 1; off < 512; off <<= 1) {
        out[t] = in[t] + (t >= off ? in[t - off] : 0);
        __syncthreads();
        int* tmp = in; in = out; out = tmp;
    }
    int excl = in[t] - v;
    if (t < NBIN) { binbase[t] = excl; gcur[t] = excl; }
    if (t == 511) { binbase[NBIN] = in[511]; rowptr[N_NODES] = in[511]; }
}

// partition edges into 391 bins; each block reserves a private contiguous
// chunk per bin (one global atomic per (block,bin)) -> every ebuf cacheline
// is written by exactly one block, once.
__global__ __launch_bounds__(256) void k_part(const int* __restrict__ src,
                                              const int* __restrict__ dst,
                                              int* __restrict__ gcur,
                                              int* __restrict__ ebuf) {
    __shared__ int lh[NBIN], gb[NBIN], cur[NBIN];
    for (int i = threadIdx.x; i < NBIN; i += 256) { lh[i] = 0; cur[i] = 0; }
    __syncthreads();
    int beg = blockIdx.x * PART_CHUNK;
    int end = min(beg + PART_CHUNK, N_EDGES);
    for (int e = beg + threadIdx.x; e < end; e += 256)
        atomicAdd(&lh[dst[e] >> 8], 1);
    __syncthreads();
    for (int i = threadIdx.x; i < NBIN; i += 256)
        gb[i] = lh[i] ? atomicAdd(&gcur[i], lh[i]) : 0;
    __syncthreads();
    for (int e = beg + threadIdx.x; e < end; e += 256) {
        int d = dst[e], s = src[e];
        int bin = d >> 8;
        int r = atomicAdd(&cur[bin], 1);
        ebuf[gb[bin] + r] = ((d & 255) << 17) | s;   // dst-low-8 | src(17b)
    }
}

// one block per bin: LDS counting-sort by dst; writes col coalesced and
// emits rowptr + dinv for its 256 nodes.
__global__ __launch_bounds__(256) void k_sortbin(const int* __restrict__ binbase,
                                                 const int* __restrict__ ebuf,
                                                 int* __restrict__ col,
                                                 int* __restrict__ rowptr,
                                                 float* __restrict__ dinv) {
    __shared__ int hc[256], sc[256], sa[256], sb[256];
    __shared__ int scol[BIN_CAP];
    int b = blockIdx.x, t = threadIdx.x;
    int d0 = b << 8;
    int e0 = binbase[b], e1 = binbase[b + 1];
    hc[t] = 0;
    __syncthreads();
    for (int i = e0 + t; i < e1; i += 256)
        atomicAdd(&hc[ebuf[i] >> 17], 1);
    __syncthreads();
    sa[t] = hc[t];
    __syncthreads();
    int* in = sa; int* out = sb;
    for (int o = 1; o < 256; o <<= 1) {
        out[t] = in[t] + (t >= o ? in[t - o] : 0);
        __syncthreads();
        int* tm = in; in = out; out = tm;
    }
    int excl = in[t] - hc[t];
    sc[t] = excl;
    int node = d0 + t;
    if (node < N_NODES) {
        rowptr[node] = e0 + excl;
        dinv[node] = rsqrtf((float)(hc[t] + 1));   // +1 self loop
    }
    __syncthreads();
    for (int i = e0 + t; i < e1; i += 256) {
        int pk = ebuf[i];
        int p = atomicAdd(&sc[pk >> 17], 1);
        if (p < BIN_CAP) scol[p] = pk & 0x1FFFF;
    }
    __syncthreads();
    int n = e1 - e0;
    for (int i = t; i < n; i += 256) col[e0 + i] = scol[i];
}

// ---------------- tiled GEMM transform ----------------
// u[node][f] = half( (A[node,:] @ W)[f] * dinv[node] )
// K-chunk 32 (16.4 KB LDS -> 8 blocks/CU), swizzled transpose store:
// element (k, m) lives at xt[k][(m + 4*(k>>2)) & 63] -> 2-way write banks
// (free) and 4-aligned broadcast reads.
template<int K>
__global__ __launch_bounds__(256) void k_gemm(const float* __restrict__ A,
                                              const float* __restrict__ W,
                                              const float* __restrict__ dinv,
                                              __half* __restrict__ u) {
    __shared__ float xt[32][64];
    __shared__ float ws[32][64];
    int t = threadIdx.x;
    int ti = t & 15;
    int tj = t >> 4;
    int node0 = blockIdx.x * 64;
    float acc[4][4] = {{0.f}};

    for (int kc = 0; kc < K; kc += 32) {
        if (kc) __syncthreads();
#pragma unroll
        for (int hh = 0; hh < 2; ++hh) {
            int f = t + 256 * hh;                       // 0..511
            // x: row m (node), cols 4c..4c+3 of this chunk
            int m = f >> 3, c = f & 7;
            int node = node0 + m;
            if (node >= N_NODES) node = N_NODES - 1;    // clamp (stores guarded)
            float4 v = *(const float4*)(A + (size_t)node * K + kc + 4 * c);
            int cs = (m + 4 * c) & 63;                  // swizzled column
            xt[4 * c + 0][cs] = v.x;
            xt[4 * c + 1][cs] = v.y;
            xt[4 * c + 2][cs] = v.z;
            xt[4 * c + 3][cs] = v.w;
            // W: row kw, cols 4cw..4cw+3 (no transpose)
            int kw = f >> 4, cw = f & 15;
            *(float4*)&ws[kw][4 * cw] =
                *(const float4*)(W + (size_t)(kc + kw) * D_H + 4 * cw);
        }
        __syncthreads();
#pragma unroll
        for (int k = 0; k < 32; ++k) {
            float4 xv = *(const float4*)&xt[k][(4 * tj + 4 * (k >> 2)) & 63];
            float4 wv = *(const float4*)&ws[k][4 * ti];
            float xa[4] = {xv.x, xv.y, xv.z, xv.w};
            float wa[4] = {wv.x, wv.y, wv.z, wv.w};
#pragma unroll
            for (int i = 0; i < 4; ++i)
#pragma unroll
                for (int j = 0; j < 4; ++j)
                    acc[i][j] = fmaf(xa[i], wa[j], acc[i][j]);
        }
    }
#pragma unroll
    for (int i = 0; i < 4; ++i) {
        int node = node0 + 4 * tj + i;
        if (node < N_NODES) {
            float dv = dinv[node];
            __half2* up = (__half2*)(u + (size_t)node * D_H + 4 * ti);
            up[0] = __floats2half2_rn(acc[i][0] * dv, acc[i][1] * dv);
            up[1] = __floats2half2_rn(acc[i][2] * dv, acc[i][3] * dv);
        }
    }
}

// ------------- aggregation: 4 edges/wave, 8 B/lane, 8-deep pipeline -------
// Wave = 4 sub-waves of 16 lanes. Sub-wave q handles edges e = beg+q (mod 4);
// lane fq covers features 4fq..4fq+3 (uint2 = 4 halves). One instruction
// gathers 4 full 128 B rows.

__device__ __forceinline__ void acc4(float4& a, uint2 w) {
    __half2 h0 = *reinterpret_cast<__half2*>(&w.x);
    __half2 h1 = *reinterpret_cast<__half2*>(&w.y);
    float2 f0 = __half22float2(h0);
    float2 f1 = __half22float2(h1);
    a.x += f0.x; a.y += f0.y; a.z += f1.x; a.w += f1.y;
}

__device__ __forceinline__ float4 agg_gather4(const __half* __restrict__ u,
                                              const int* __restrict__ col,
                                              int beg, int end, int q, int fq) {
    float4 acc = make_float4(0.f, 0.f, 0.f, 0.f);
    int base = beg;
    for (; base + 31 < end; base += 32) {        // 32 edges/iter, 8 per sub-wave
        int e = base + q;
        int s0 = col[e],      s1 = col[e + 4],  s2 = col[e + 8],  s3 = col[e + 12];
        int s4 = col[e + 16], s5 = col[e + 20], s6 = col[e + 24], s7 = col[e + 28];
        uint2 w0 = *(const uint2*)(u + (size_t)s0 * D_H + fq * 4);
        uint2 w1 = *(const uint2*)(u + (size_t)s1 * D_H + fq * 4);
        uint2 w2 = *(const uint2*)(u + (size_t)s2 * D_H + fq * 4);
        uint2 w3 = *(const uint2*)(u + (size_t)s3 * D_H + fq * 4);
        uint2 w4 = *(const uint2*)(u + (size_t)s4 * D_H + fq * 4);
        uint2 w5 = *(const uint2*)(u + (size_t)s5 * D_H + fq * 4);
        uint2 w6 = *(const uint2*)(u + (size_t)s6 * D_H + fq * 4);
        uint2 w7 = *(const uint2*)(u + (size_t)s7 * D_H + fq * 4);
        acc4(acc, w0); acc4(acc, w1); acc4(acc, w2); acc4(acc, w3);
        acc4(acc, w4); acc4(acc, w5); acc4(acc, w6); acc4(acc, w7);
    }
    for (int e = base + q; e < end; e += 4) {    // remainder (divergent, <=8 iters)
        uint2 w = *(const uint2*)(u + (size_t)col[e] * D_H + fq * 4);
        acc4(acc, w);
    }
    return acc;
}

// h[i] = relu( dinv[i] * (sum u[src] + u[i]) + b )
__global__ __launch_bounds__(256) void k_agg(const __half* __restrict__ u,
                                             const int* __restrict__ rowptr,
                                             const int* __restrict__ col,
                                             const float* __restrict__ dinv,
                                             const float* __restrict__ b,
                                             float* __restrict__ h) {
    int t = threadIdx.x;
    int lane = t & 63, q = lane >> 4, fq = lane & 15;
    int node = (blockIdx.x * blockDim.x + t) >> 6;
    if (node >= N_NODES) return;
    float4 acc = agg_gather4(u, col, rowptr[node], rowptr[node + 1], q, fq);
    if (q == 0) {                                // self loop, counted once
        uint2 w = *(const uint2*)(u + (size_t)node * D_H + fq * 4);
        acc4(acc, w);
    }
    // combine the 4 sub-waves (lanes share fq)
    acc.x += __shfl_xor(acc.x, 16, 64); acc.y += __shfl_xor(acc.y, 16, 64);
    acc.z += __shfl_xor(acc.z, 16, 64); acc.w += __shfl_xor(acc.w, 16, 64);
    acc.x += __shfl_xor(acc.x, 32, 64); acc.y += __shfl_xor(acc.y, 32, 64);
    acc.z += __shfl_xor(acc.z, 32, 64); acc.w += __shfl_xor(acc.w, 32, 64);
    if (q == 0) {
        float dv = dinv[node];
        float4 bb = *(const float4*)(b + 4 * fq);
        float4 o;
        o.x = fmaxf(acc.x * dv + bb.x, 0.f);
        o.y = fmaxf(acc.y * dv + bb.y, 0.f);
        o.z = fmaxf(acc.z * dv + bb.z, 0.f);
        o.w = fmaxf(acc.w * dv + bb.w, 0.f);
        *(float4*)(h + (size_t)node * D_H + 4 * fq) = o;
    }
}

// layer 3 + head: val[i] = dot(agg_row*dinv + b, Wl)
__global__ __launch_bounds__(256) void k_agg_dot(const __half* __restrict__ uin,
                                                 const int* __restrict__ rowptr,
                                                 const int* __restrict__ col,
                                                 const float* __restrict__ dinv,
                                                 const float* __restrict__ b,
                                                 const float* __restrict__ Wl,
                                                 float* __restrict__ val) {
    int t = threadIdx.x;
    int lane = t & 63, q = lane >> 4, fq = lane & 15;
    int node = (blockIdx.x * blockDim.x + t) >> 6;
    if (node >= N_NODES) return;
    float4 acc = agg_gather4(uin, col, rowptr[node], rowptr[node + 1], q, fq);
    if (q == 0) {                                // self loop, counted once
        uint2 w = *(const uint2*)(uin + (size_t)node * D_H + fq * 4);
        acc4(acc, w);
    }
    float4 wl = *(const float4*)(Wl + 4 * fq);
    float dv = dinv[node];
    float v = dv * (acc.x * wl.x + acc.y * wl.y + acc.z * wl.z + acc.w * wl.w);
    if (q == 0) {                                // bias term, counted once
        float4 bb = *(const float4*)(b + 4 * fq);
        v += bb.x * wl.x + bb.y * wl.y + bb.z * wl.z + bb.w * wl.w;
    }
#pragma unroll
    for (int m = 32; m > 0; m >>= 1) v += __shfl_xor(v, m, 64);
    if (lane == 0) val[node] = v;
}

// one block per graph: batch is sorted, binary-search the segment, reduce.
__global__ __launch_bounds__(256) void k_gpool(const float* __restrict__ val,
                                               const int* __restrict__ batch,
                                               const float* __restrict__ bl,
                                               float* __restrict__ out) {
    int g = blockIdx.x;
    int l = 0, r = N_NODES;
    while (l < r) { int m = (l + r) >> 1; if (batch[m] < g) l = m + 1; else r = m; }
    int lo = l;
    r = N_NODES;
    while (l < r) { int m = (l + r) >> 1; if (batch[m] < g + 1) l = m + 1; else r = m; }
    int hi = l;
    float s = 0.0f;
    for (int i = lo + threadIdx.x; i < hi; i += 256) s += val[i];
#pragma unroll
    for (int m = 32; m > 0; m >>= 1) s += __shfl_xor(s, m, 64);
    __shared__ float red[4];
    int wid = threadIdx.x >> 6, lane = threadIdx.x & 63;
    if (lane == 0) red[wid] = s;
    __syncthreads();
    if (threadIdx.x == 0) {
        float t = red[0] + red[1] + red[2] + red[3];
        out[g] = t / fmaxf((float)(hi - lo), 1.0f) + bl[0];
    }
}

// ---------------- launch ----------------

extern "C" void kernel_launch(void* const* d_in, const int* in_sizes, int n_in,
                              void* d_out, int out_size, void* d_ws, size_t ws_size,
                              hipStream_t stream) {
    const float* x   = (const float*)d_in[0];
    const int*   ei  = (const int*)d_in[1];
    const int*   bat = (const int*)d_in[2];
    const float* W1  = (const float*)d_in[3];
    const float* b1  = (const float*)d_in[4];
    const float* W2  = (const float*)d_in[5];
    const float* b2  = (const float*)d_in[6];
    const float* W3  = (const float*)d_in[7];
    const float* b3  = (const float*)d_in[8];
    const float* Wl  = (const float*)d_in[9];
    const float* bl  = (const float*)d_in[10];
    float* out = (float*)d_out;

    char* p = (char*)d_ws;
    auto alloc = [&](size_t bytes) -> void* {
        void* r = (void*)p;
        p += (bytes + 255) & ~(size_t)255;
        return r;
    };
    int*    ghist   = (int*)alloc((size_t)NBIN * 4);
    int*    binbase = (int*)alloc((size_t)(NBIN + 1) * 4);
    int*    gcur    = (int*)alloc((size_t)NBIN * 4);
    int*    rowptr  = (int*)alloc((size_t)(N_NODES + 1) * 4);
    float*  dinv    = (float*)alloc((size_t)N_NODES * 4);
    int*    colb    = (int*)alloc((size_t)N_EDGES * 4);
    int*    ebuf    = (int*)alloc((size_t)N_EDGES * 4);
    __half* u1      = (__half*)alloc((size_t)N_NODES * D_H * 2);
    __half* u2      = (__half*)alloc((size_t)N_NODES * D_H * 2);
    float*  h       = (float*)alloc((size_t)N_NODES * D_H * 4);
    float*  val     = (float*)alloc((size_t)N_NODES * 4);

    hipMemsetAsync(ghist, 0, (size_t)NBIN * 4, stream);

    const int* srcp = ei;
    const int* dstp = ei + N_EDGES;

    int wbl = (N_NODES * 64 + 255) / 256;           // one wave per node
    int gbl = (N_NODES + 63) / 64;

    // CSR build
    k_hist<<<HIST_BLOCKS, 256, 0, stream>>>(dstp, ghist);
    k_scanbins<<<1, 512, 0, stream>>>(ghist, binbase, gcur, rowptr);
    k_part<<<PART_BLOCKS, 256, 0, stream>>>(srcp, dstp, gcur, ebuf);
    k_sortbin<<<NBIN, 256, 0, stream>>>(binbase, ebuf, colb, rowptr, dinv);

    // layer 1: 320 -> 64
    k_gemm<D_IN><<<gbl, 256, 0, stream>>>(x, W1, dinv, u1);
    k_agg<<<wbl, 256, 0, stream>>>(u1, rowptr, colb, dinv, b1, h);
    // layer 2: 64 -> 64
    k_gemm<D_H><<<gbl, 256, 0, stream>>>(h, W2, dinv, u2);
    k_agg<<<wbl, 256, 0, stream>>>(u2, rowptr, colb, dinv, b2, h);
    // layer 3: 64 -> 64, fused with linear head dot
    k_gemm<D_H><<<gbl, 256, 0, stream>>>(h, W3, dinv, u1);
    k_agg_dot<<<wbl, 256, 0, stream>>>(u1, rowptr, colb, dinv, b3, Wl, val);

    // pooling
    k_gpool<<<N_GRAPHS, 256, 0, stream>>>(val, bat, bl, out);
}

// Round 14
// 388.230 us; speedup vs baseline: 9.7074x; 1.1157x over previous
//
#include <hip/hip_runtime.h>
#include <hip/hip_bf16.h>
#include <hip/hip_fp16.h>

#define N_NODES 100000
#define N_EDGES 3200000
#define N_GRAPHS 256
#define D_IN 320
#define D_H 64

#define NBIN 391                    // ceil(N_NODES / 256) bins of 256 dst nodes
#define BIN_CAP 14336               // padded bin ~12154, sigma~172 -> +12 sigma
#define HIST_BLOCKS 256
#define HIST_CHUNK ((N_EDGES + HIST_BLOCKS - 1) / HIST_BLOCKS)
#define PART_BLOCKS 200
#define PART_CHUNK ((N_EDGES + PART_BLOCKS - 1) / PART_BLOCKS)   // 16000
#define COLB_CAP 5500000            // padded edges ~4.75M

// ---------------- CSR build (block-private chunk partition) ----------------

__global__ __launch_bounds__(256) void k_hist(const int* __restrict__ dst,
                                              int* __restrict__ ghist) {
    __shared__ int lh[NBIN];
    for (int i = threadIdx.x; i < NBIN; i += 256) lh[i] = 0;
    __syncthreads();
    int beg = blockIdx.x * HIST_CHUNK;
    int end = min(beg + HIST_CHUNK, N_EDGES);
    for (int e = beg + threadIdx.x; e < end; e += 256)
        atomicAdd(&lh[dst[e] >> 8], 1);
    __syncthreads();
    for (int i = threadIdx.x; i < NBIN; i += 256)
        if (lh[i]) atomicAdd(&ghist[i], lh[i]);
}

// scan real bin counts -> compact binbase (for ebuf) + gcur
__global__ __launch_bounds__(512) void k_scanbins(const int* __restrict__ ghist,
                                                  int* __restrict__ binbase,
                                                  int* __restrict__ gcur) {
    __shared__ int sa[512], sb[512];
    int t = threadIdx.x;
    int v = (t < NBIN) ? ghist[t] : 0;
    sa[t] = v;
    __syncthreads();
    int* in = sa; int* out = sb;
    for (int off = 1; off < 512; off <<= 1) {
        out[t] = in[t] + (t >= off ? in[t - off] : 0);
        __syncthreads();
        int* tmp = in; in = out; out = tmp;
    }
    int excl = in[t] - v;
    if (t < NBIN) { binbase[t] = excl; gcur[t] = excl; }
    if (t == 511) binbase[NBIN] = in[511];
}

// partition edges into 391 bins; block-private contiguous chunks per bin.
__global__ __launch_bounds__(256) void k_part(const int* __restrict__ src,
                                              const int* __restrict__ dst,
                                              int* __restrict__ gcur,
                                              int* __restrict__ ebuf) {
    __shared__ int lh[NBIN], gb[NBIN], cur[NBIN];
    for (int i = threadIdx.x; i < NBIN; i += 256) { lh[i] = 0; cur[i] = 0; }
    __syncthreads();
    int beg = blockIdx.x * PART_CHUNK;
    int end = min(beg + PART_CHUNK, N_EDGES);
    for (int e = beg + threadIdx.x; e < end; e += 256)
        atomicAdd(&lh[dst[e] >> 8], 1);
    __syncthreads();
    for (int i = threadIdx.x; i < NBIN; i += 256)
        gb[i] = lh[i] ? atomicAdd(&gcur[i], lh[i]) : 0;
    __syncthreads();
    for (int e = beg + threadIdx.x; e < end; e += 256) {
        int d = dst[e], s = src[e];
        int bin = d >> 8;
        int r = atomicAdd(&cur[bin], 1);
        ebuf[gb[bin] + r] = ((d & 255) << 17) | s;   // dst-low-8 | src(17b)
    }
}

// per bin: per-node degree -> padded degree (mult of 32), local padded
// offsets (lofs), dinv, padded bin total.
__global__ __launch_bounds__(256) void k_binpad(const int* __restrict__ binbase,
                                                const int* __restrict__ ebuf,
                                                int* __restrict__ pbin,
                                                int* __restrict__ lofs,
                                                float* __restrict__ dinv) {
    __shared__ int hc[256], sa[256], sb[256];
    int b = blockIdx.x, t = threadIdx.x;
    int e0 = binbase[b], e1 = binbase[b + 1];
    hc[t] = 0;
    __syncthreads();
    for (int i = e0 + t; i < e1; i += 256)
        atomicAdd(&hc[ebuf[i] >> 17], 1);
    __syncthreads();
    int deg = hc[t];
    int pdeg = (deg + 31) & ~31;
    sa[t] = pdeg;
    __syncthreads();
    int* in = sa; int* out = sb;
    for (int o = 1; o < 256; o <<= 1) {
        out[t] = in[t] + (t >= o ? in[t - o] : 0);
        __syncthreads();
        int* tm = in; in = out; out = tm;
    }
    int excl = in[t] - pdeg;
    lofs[(b << 8) + t] = excl;
    int node = (b << 8) + t;
    if (node < N_NODES) dinv[node] = rsqrtf((float)(deg + 1));  // +1 self loop
    if (t == 255) pbin[b] = in[255];
}

// scan padded bin totals -> pbinbase; also prowptr[N] and u's zero pad row.
__global__ __launch_bounds__(512) void k_scanp(const int* __restrict__ pbin,
                                               int* __restrict__ pbinbase,
                                               int* __restrict__ prowptr,
                                               __half* __restrict__ u) {
    __shared__ int sa[512], sb[512];
    int t = threadIdx.x;
    int v = (t < NBIN) ? pbin[t] : 0;
    sa[t] = v;
    __syncthreads();
    int* in = sa; int* out = sb;
    for (int off = 1; off < 512; off <<= 1) {
        out[t] = in[t] + (t >= off ? in[t - off] : 0);
        __syncthreads();
        int* tmp = in; in = out; out = tmp;
    }
    int excl = in[t] - v;
    if (t < NBIN) pbinbase[t] = excl;
    if (t == 511) { pbinbase[NBIN] = in[511]; prowptr[N_NODES] = in[511]; }
    if (t < 32) ((unsigned*)(u + (size_t)N_NODES * D_H))[t] = 0u;  // zero row
}

// per bin: place edges at padded local offsets, fill pads with sentinel,
// write col coalesced; emit prowptr.
__global__ __launch_bounds__(256) void k_sortbin(const int* __restrict__ binbase,
                                                 const int* __restrict__ pbinbase,
                                                 const int* __restrict__ lofs,
                                                 const int* __restrict__ ebuf,
                                                 int* __restrict__ col,
                                                 int* __restrict__ prowptr) {
    __shared__ int hc[256], sc[256];
    __shared__ int scol[BIN_CAP];
    int b = blockIdx.x, t = threadIdx.x;
    int d0 = b << 8;
    int e0 = binbase[b], e1 = binbase[b + 1];
    int pb0 = pbinbase[b], pb1 = pbinbase[b + 1];
    hc[t] = 0;
    __syncthreads();
    for (int i = e0 + t; i < e1; i += 256)
        atomicAdd(&hc[ebuf[i] >> 17], 1);
    __syncthreads();
    int lb = lofs[d0 + t];
    int deg = hc[t];
    int pdeg = (deg + 31) & ~31;
    sc[t] = lb;
    int node = d0 + t;
    if (node < N_NODES) prowptr[node] = pb0 + lb;
    __syncthreads();
    for (int i = e0 + t; i < e1; i += 256) {
        int pk = ebuf[i];
        int p = atomicAdd(&sc[pk >> 17], 1);
        if (p < BIN_CAP) scol[p] = pk & 0x1FFFF;
    }
    __syncthreads();
    for (int j = lb + deg; j < lb + pdeg; ++j)
        if (j < BIN_CAP) scol[j] = N_NODES;          // sentinel -> zero row
    __syncthreads();
    int n = pb1 - pb0;
    for (int i = t; i < n; i += 256) col[pb0 + i] = scol[i];
}

// ---------------- tiled GEMM transform ----------------
// u[node][f] = half( (A[node,:] @ W)[f] * dinv[node] )
// K-chunk 32 (16.4 KB LDS -> 8 blocks/CU), swizzled transpose store.
template<int K>
__global__ __launch_bounds__(256) void k_gemm(const float* __restrict__ A,
                                              const float* __restrict__ W,
                                              const float* __restrict__ dinv,
                                              __half* __restrict__ u) {
    __shared__ float xt[32][64];
    __shared__ float ws[32][64];
    int t = threadIdx.x;
    int ti = t & 15;
    int tj = t >> 4;
    int node0 = blockIdx.x * 64;
    float acc[4][4] = {{0.f}};

    for (int kc = 0; kc < K; kc += 32) {
        if (kc) __syncthreads();
#pragma unroll
        for (int hh = 0; hh < 2; ++hh) {
            int f = t + 256 * hh;                       // 0..511
            int m = f >> 3, c = f & 7;
            int node = node0 + m;
            if (node >= N_NODES) node = N_NODES - 1;    // clamp (stores guarded)
            float4 v = *(const float4*)(A + (size_t)node * K + kc + 4 * c);
            int cs = (m + 4 * c) & 63;                  // swizzled column
            xt[4 * c + 0][cs] = v.x;
            xt[4 * c + 1][cs] = v.y;
            xt[4 * c + 2][cs] = v.z;
            xt[4 * c + 3][cs] = v.w;
            int kw = f >> 4, cw = f & 15;
            *(float4*)&ws[kw][4 * cw] =
                *(const float4*)(W + (size_t)(kc + kw) * D_H + 4 * cw);
        }
        __syncthreads();
#pragma unroll
        for (int k = 0; k < 32; ++k) {
            float4 xv = *(const float4*)&xt[k][(4 * tj + 4 * (k >> 2)) & 63];
            float4 wv = *(const float4*)&ws[k][4 * ti];
            float xa[4] = {xv.x, xv.y, xv.z, xv.w};
            float wa[4] = {wv.x, wv.y, wv.z, wv.w};
#pragma unroll
            for (int i = 0; i < 4; ++i)
#pragma unroll
                for (int j = 0; j < 4; ++j)
                    acc[i][j] = fmaf(xa[i], wa[j], acc[i][j]);
        }
    }
#pragma unroll
    for (int i = 0; i < 4; ++i) {
        int node = node0 + 4 * tj + i;
        if (node < N_NODES) {
            float dv = dinv[node];
            __half2* up = (__half2*)(u + (size_t)node * D_H + 4 * ti);
            up[0] = __floats2half2_rn(acc[i][0] * dv, acc[i][1] * dv);
            up[1] = __floats2half2_rn(acc[i][2] * dv, acc[i][3] * dv);
        }
    }
}

// ------------- aggregation: 4 edges/wave, 8 B/lane, 8-deep pipeline -------
// Lists are padded to multiples of 32 -> remainder loop never runs; every
// edge flows through the full 8-deep pipeline.

__device__ __forceinline__ void acc4(float4& a, uint2 w) {
    __half2 h0 = *reinterpret_cast<__half2*>(&w.x);
    __half2 h1 = *reinterpret_cast<__half2*>(&w.y);
    float2 f0 = __half22float2(h0);
    float2 f1 = __half22float2(h1);
    a.x += f0.x; a.y += f0.y; a.z += f1.x; a.w += f1.y;
}

__device__ __forceinline__ float4 agg_gather4(const __half* __restrict__ u,
                                              const int* __restrict__ col,
                                              int beg, int end, int q, int fq) {
    float4 acc = make_float4(0.f, 0.f, 0.f, 0.f);
    int base = beg;
    for (; base + 31 < end; base += 32) {        // 32 edges/iter, 8 per sub-wave
        int e = base + q;
        int s0 = col[e],      s1 = col[e + 4],  s2 = col[e + 8],  s3 = col[e + 12];
        int s4 = col[e + 16], s5 = col[e + 20], s6 = col[e + 24], s7 = col[e + 28];
        uint2 w0 = *(const uint2*)(u + (size_t)s0 * D_H + fq * 4);
        uint2 w1 = *(const uint2*)(u + (size_t)s1 * D_H + fq * 4);
        uint2 w2 = *(const uint2*)(u + (size_t)s2 * D_H + fq * 4);
        uint2 w3 = *(const uint2*)(u + (size_t)s3 * D_H + fq * 4);
        uint2 w4 = *(const uint2*)(u + (size_t)s4 * D_H + fq * 4);
        uint2 w5 = *(const uint2*)(u + (size_t)s5 * D_H + fq * 4);
        uint2 w6 = *(const uint2*)(u + (size_t)s6 * D_H + fq * 4);
        uint2 w7 = *(const uint2*)(u + (size_t)s7 * D_H + fq * 4);
        acc4(acc, w0); acc4(acc, w1); acc4(acc, w2); acc4(acc, w3);
        acc4(acc, w4); acc4(acc, w5); acc4(acc, w6); acc4(acc, w7);
    }
    for (int e = base + q; e < end; e += 4) {    // safety; never runs (padded)
        uint2 w = *(const uint2*)(u + (size_t)col[e] * D_H + fq * 4);
        acc4(acc, w);
    }
    return acc;
}

// h[i] = relu( dinv[i] * (sum u[src] + u[i]) + b )
__global__ __launch_bounds__(256) void k_agg(const __half* __restrict__ u,
                                             const int* __restrict__ prowptr,
                                             const int* __restrict__ col,
                                             const float* __restrict__ dinv,
                                             const float* __restrict__ b,
                                             float* __restrict__ h) {
    int t = threadIdx.x;
    int lane = t & 63, q = lane >> 4, fq = lane & 15;
    int node = (blockIdx.x * blockDim.x + t) >> 6;
    if (node >= N_NODES) return;
    float4 acc = agg_gather4(u, col, prowptr[node], prowptr[node + 1], q, fq);
    if (q == 0) {                                // self loop, counted once
        uint2 w = *(const uint2*)(u + (size_t)node * D_H + fq * 4);
        acc4(acc, w);
    }
    acc.x += __shfl_xor(acc.x, 16, 64); acc.y += __shfl_xor(acc.y, 16, 64);
    acc.z += __shfl_xor(acc.z, 16, 64); acc.w += __shfl_xor(acc.w, 16, 64);
    acc.x += __shfl_xor(acc.x, 32, 64); acc.y += __shfl_xor(acc.y, 32, 64);
    acc.z += __shfl_xor(acc.z, 32, 64); acc.w += __shfl_xor(acc.w, 32, 64);
    if (q == 0) {
        float dv = dinv[node];
        float4 bb = *(const float4*)(b + 4 * fq);
        float4 o;
        o.x = fmaxf(acc.x * dv + bb.x, 0.f);
        o.y = fmaxf(acc.y * dv + bb.y, 0.f);
        o.z = fmaxf(acc.z * dv + bb.z, 0.f);
        o.w = fmaxf(acc.w * dv + bb.w, 0.f);
        *(float4*)(h + (size_t)node * D_H + 4 * fq) = o;
    }
}

// layer 3 + head: val[i] = dot(agg_row*dinv + b, Wl)
__global__ __launch_bounds__(256) void k_agg_dot(const __half* __restrict__ uin,
                                                 const int* __restrict__ prowptr,
                                                 const int* __restrict__ col,
                                                 const float* __restrict__ dinv,
                                                 const float* __restrict__ b,
                                                 const float* __restrict__ Wl,
                                                 float* __restrict__ val) {
    int t = threadIdx.x;
    int lane = t & 63, q = lane >> 4, fq = lane & 15;
    int node = (blockIdx.x * blockDim.x + t) >> 6;
    if (node >= N_NODES) return;
    float4 acc = agg_gather4(uin, col, prowptr[node], prowptr[node + 1], q, fq);
    if (q == 0) {                                // self loop, counted once
        uint2 w = *(const uint2*)(uin + (size_t)node * D_H + fq * 4);
        acc4(acc, w);
    }
    float4 wl = *(const float4*)(Wl + 4 * fq);
    float dv = dinv[node];
    float v = dv * (acc.x * wl.x + acc.y * wl.y + acc.z * wl.z + acc.w * wl.w);
    if (q == 0) {                                // bias term, counted once
        float4 bb = *(const float4*)(b + 4 * fq);
        v += bb.x * wl.x + bb.y * wl.y + bb.z * wl.z + bb.w * wl.w;
    }
#pragma unroll
    for (int m = 32; m > 0; m >>= 1) v += __shfl_xor(v, m, 64);
    if (lane == 0) val[node] = v;
}

// one block per graph: batch is sorted, binary-search the segment, reduce.
__global__ __launch_bounds__(256) void k_gpool(const float* __restrict__ val,
                                               const int* __restrict__ batch,
                                               const float* __restrict__ bl,
                                               float* __restrict__ out) {
    int g = blockIdx.x;
    int l = 0, r = N_NODES;
    while (l < r) { int m = (l + r) >> 1; if (batch[m] < g) l = m + 1; else r = m; }
    int lo = l;
    r = N_NODES;
    while (l < r) { int m = (l + r) >> 1; if (batch[m] < g + 1) l = m + 1; else r = m; }
    int hi = l;
    float s = 0.0f;
    for (int i = lo + threadIdx.x; i < hi; i += 256) s += val[i];
#pragma unroll
    for (int m = 32; m > 0; m >>= 1) s += __shfl_xor(s, m, 64);
    __shared__ float red[4];
    int wid = threadIdx.x >> 6, lane = threadIdx.x & 63;
    if (lane == 0) red[wid] = s;
    __syncthreads();
    if (threadIdx.x == 0) {
        float t = red[0] + red[1] + red[2] + red[3];
        out[g] = t / fmaxf((float)(hi - lo), 1.0f) + bl[0];
    }
}

// ---------------- launch ----------------

extern "C" void kernel_launch(void* const* d_in, const int* in_sizes, int n_in,
                              void* d_out, int out_size, void* d_ws, size_t ws_size,
                              hipStream_t stream) {
    const float* x   = (const float*)d_in[0];
    const int*   ei  = (const int*)d_in[1];
    const int*   bat = (const int*)d_in[2];
    const float* W1  = (const float*)d_in[3];
    const float* b1  = (const float*)d_in[4];
    const float* W2  = (const float*)d_in[5];
    const float* b2  = (const float*)d_in[6];
    const float* W3  = (const float*)d_in[7];
    const float* b3  = (const float*)d_in[8];
    const float* Wl  = (const float*)d_in[9];
    const float* bl  = (const float*)d_in[10];
    float* out = (float*)d_out;

    char* p = (char*)d_ws;
    auto alloc = [&](size_t bytes) -> void* {
        void* r = (void*)p;
        p += (bytes + 255) & ~(size_t)255;
        return r;
    };
    int*    ghist    = (int*)alloc((size_t)NBIN * 4);
    int*    binbase  = (int*)alloc((size_t)(NBIN + 1) * 4);
    int*    gcur     = (int*)alloc((size_t)NBIN * 4);
    int*    pbin     = (int*)alloc((size_t)NBIN * 4);
    int*    pbinbase = (int*)alloc((size_t)(NBIN + 1) * 4);
    int*    lofs     = (int*)alloc((size_t)NBIN * 256 * 4);
    int*    prowptr  = (int*)alloc((size_t)(N_NODES + 1) * 4);
    float*  dinv     = (float*)alloc((size_t)N_NODES * 4);
    int*    colb     = (int*)alloc((size_t)COLB_CAP * 4);
    int*    ebuf     = (int*)alloc((size_t)N_EDGES * 4);
    __half* u        = (__half*)alloc((size_t)(N_NODES + 1) * D_H * 2);
    float*  h        = (float*)alloc((size_t)N_NODES * D_H * 4);
    float*  val      = (float*)alloc((size_t)N_NODES * 4);

    hipMemsetAsync(ghist, 0, (size_t)NBIN * 4, stream);

    const int* srcp = ei;
    const int* dstp = ei + N_EDGES;

    int wbl = (N_NODES * 64 + 255) / 256;           // one wave per node
    int gbl = (N_NODES + 63) / 64;

    // CSR build (padded lists, sentinel -> zero row)
    k_hist<<<HIST_BLOCKS, 256, 0, stream>>>(dstp, ghist);
    k_scanbins<<<1, 512, 0, stream>>>(ghist, binbase, gcur);
    k_part<<<PART_BLOCKS, 256, 0, stream>>>(srcp, dstp, gcur, ebuf);
    k_binpad<<<NBIN, 256, 0, stream>>>(binbase, ebuf, pbin, lofs, dinv);
    k_scanp<<<1, 512, 0, stream>>>(pbin, pbinbase, prowptr, u);
    k_sortbin<<<NBIN, 256, 0, stream>>>(binbase, pbinbase, lofs, ebuf, colb, prowptr);

    // layer 1: 320 -> 64
    k_gemm<D_IN><<<gbl, 256, 0, stream>>>(x, W1, dinv, u);
    k_agg<<<wbl, 256, 0, stream>>>(u, prowptr, colb, dinv, b1, h);
    // layer 2: 64 -> 64
    k_gemm<D_H><<<gbl, 256, 0, stream>>>(h, W2, dinv, u);
    k_agg<<<wbl, 256, 0, stream>>>(u, prowptr, colb, dinv, b2, h);
    // layer 3: 64 -> 64, fused with linear head dot
    k_gemm<D_H><<<gbl, 256, 0, stream>>>(h, W3, dinv, u);
    k_agg_dot<<<wbl, 256, 0, stream>>>(u, prowptr, colb, dinv, b3, Wl, val);

    // pooling
    k_gpool<<<N_GRAPHS, 256, 0, stream>>>(val, bat, bl, out);
}